// Round 9
// baseline (295.645 us; speedup 1.0000x reference)
//
#include <hip/hip_runtime.h>
#include <cstdint>
#include <cstddef>

typedef unsigned short u16;
typedef __attribute__((ext_vector_type(8))) short bf16x8;
typedef __attribute__((ext_vector_type(4))) float f32x4;

#define DEV static __device__ __forceinline__

DEV void gload_lds16(const void* g, void* l) {
  __builtin_amdgcn_global_load_lds((const __attribute__((address_space(1))) void*)g,
                                   (__attribute__((address_space(3))) void*)l, 16, 0, 0);
}

DEV u16 f2bf(float f) {  // RNE fp32 -> bf16 (finite inputs)
  unsigned x = __float_as_uint(f);
  return (u16)((x + 0x7FFFu + ((x >> 16) & 1u)) >> 16);
}

DEV unsigned cvtpk(float lo, float hi) {  // bf16(lo) in [15:0], bf16(hi) in [31:16]
  unsigned r;
  asm("v_cvt_pk_bf16_f32 %0, %1, %2" : "=v"(r) : "v"(lo), "v"(hi));
  return r;
}

#if __has_builtin(__builtin_amdgcn_exp2f)
DEV float fexp2(float x) { return __builtin_amdgcn_exp2f(x); }
#else
DEV float fexp2(float x) { return exp2f(x); }
#endif

// counted vmcnt wait + scheduling fence (rule #18)
#define WAITV(n)                                                   \
  do {                                                             \
    asm volatile("s_waitcnt vmcnt(" #n ")" ::: "memory");          \
    __builtin_amdgcn_sched_barrier(0);                             \
  } while (0)

DEV void sbar() {
  __builtin_amdgcn_sched_barrier(0);
  __builtin_amdgcn_s_barrier();
  __builtin_amdgcn_sched_barrier(0);
}

// ---------------- fp32 -> bf16 convert, 3 buffers in one launch ----------------
__global__ __launch_bounds__(256) void cvt3(const float* __restrict__ a, u16* __restrict__ da,
                                            const float* __restrict__ b, u16* __restrict__ db,
                                            const float* __restrict__ c, u16* __restrict__ dc) {
  int bid = blockIdx.x;
  const float* s;
  u16* d;
  int base;
  if (bid < 4096) { s = a; d = da; base = bid; }
  else if (bid < 7168) { s = b; d = db; base = bid - 4096; }
  else { s = c; d = dc; base = bid - 7168; }
  const int i = (base * 256 + (int)threadIdx.x) * 4;
  float4 v = *(const float4*)(s + i);
  uint2 p;
  p.x = (unsigned)f2bf(v.x) | ((unsigned)f2bf(v.y) << 16);
  p.y = (unsigned)f2bf(v.z) | ((unsigned)f2bf(v.w) << 16);
  *(uint2*)(d + i) = p;
}

// ---------------- GEMM: C = A * B^T (+bias) ----------------
// A[M][K] bf16 row-major, Bm[N][K] bf16 row-major.
// EPI 0: Cout = float[M][N], v + bias[e]
// EPI 1: QKV scatter: Q,K -> [which][b*16+h][s][d] bf16; V -> Vt[b*16+h][d][s] (transposed)
template <int EPI, int BM, int BN>
__global__ __launch_bounds__(256) void gemm_bt(const u16* __restrict__ A,
                                               const u16* __restrict__ Bm,
                                               const float* __restrict__ bias,
                                               void* __restrict__ Cout,
                                               u16* __restrict__ Vt,
                                               int M, int N, int K) {
  __shared__ u16 As[2][BM * 32];
  __shared__ u16 Bs[2][BN * 32];
  constexpr int MT = BM / 32, NT = BN / 32;
  const int cpx = (int)gridDim.x >> 3;
  const int bid = ((int)blockIdx.x & 7) * cpx + ((int)blockIdx.x >> 3);  // XCD chunking
  const int nb = N / BN;
  const int m0 = (bid / nb) * BM;
  const int n0 = (bid % nb) * BN;
  const int tid = threadIdx.x;
  const int w = tid >> 6, lane = tid & 63;
  const int wm = (w >> 1) * (BM / 2), wn = (w & 1) * (BN / 2);
  const int lr = lane & 15, lg = lane >> 4;

  f32x4 acc[MT][NT];
  const f32x4 z4 = {0.f, 0.f, 0.f, 0.f};
#pragma unroll
  for (int m = 0; m < MT; ++m)
#pragma unroll
    for (int n = 0; n < NT; ++n) acc[m][n] = z4;

  auto stage = [&](int ks, int buf) {
    const int k0 = ks << 5;
#pragma unroll
    for (int i = 0; i < BM * 4 / 256; ++i) {
      const int o = i * 256 + tid;
      const int row = o >> 2, c = o & 3;
      gload_lds16(A + (size_t)(m0 + row) * K + k0 + c * 8, &As[buf][(i * 256 + w * 64) * 8]);
    }
#pragma unroll
    for (int i = 0; i < BN * 4 / 256; ++i) {
      const int o = i * 256 + tid;
      const int row = o >> 2, c = o & 3;
      gload_lds16(Bm + (size_t)(n0 + row) * K + k0 + c * 8, &Bs[buf][(i * 256 + w * 64) * 8]);
    }
  };

  const int nk = K >> 5;
  stage(0, 0);
  __syncthreads();
  for (int ks = 0; ks < nk; ++ks) {
    const int cur = ks & 1;
    if (ks + 1 < nk) stage(ks + 1, cur ^ 1);
    bf16x8 af[MT], bfr[NT];
#pragma unroll
    for (int m = 0; m < MT; ++m)
      af[m] = *(const bf16x8*)&As[cur][(wm + m * 16 + lr) * 32 + lg * 8];
#pragma unroll
    for (int n = 0; n < NT; ++n)
      bfr[n] = *(const bf16x8*)&Bs[cur][(wn + n * 16 + lr) * 32 + lg * 8];
    __builtin_amdgcn_s_setprio(1);
#pragma unroll
    for (int m = 0; m < MT; ++m)
#pragma unroll
      for (int n = 0; n < NT; ++n)
        acc[m][n] = __builtin_amdgcn_mfma_f32_16x16x32_bf16(af[m], bfr[n], acc[m][n], 0, 0, 0);
    __builtin_amdgcn_s_setprio(0);
    __syncthreads();
  }

#pragma unroll
  for (int n = 0; n < NT; ++n) {
    const int e = n0 + wn + n * 16 + lr;
    const float bv = bias[e];
    if (EPI == 1 && (e >> 10) == 2) {
      // V: write transposed [bh][d][s], 4 consecutive s packed per store
      const int h = (e >> 6) & 15, d = e & 63;
#pragma unroll
      for (int m = 0; m < MT; ++m) {
        const int row0 = m0 + wm + m * 16 + lg * 4;
        const int bb = row0 >> 11, s0 = row0 & 2047;
        uint2 pv;
        pv.x = cvtpk(acc[m][n][0] + bv, acc[m][n][1] + bv);
        pv.y = cvtpk(acc[m][n][2] + bv, acc[m][n][3] + bv);
        *(uint2*)(Vt + (size_t)(bb * 16 + h) * 131072 + (size_t)d * 2048 + s0) = pv;
      }
    } else {
#pragma unroll
      for (int m = 0; m < MT; ++m) {
#pragma unroll
        for (int r = 0; r < 4; ++r) {
          const int row = m0 + wm + m * 16 + lg * 4 + r;  // D: col=lane&15, row=(lane>>4)*4+r
          const float v = acc[m][n][r] + bv;
          if (EPI == 0) {
            ((float*)Cout)[(size_t)row * N + e] = v;
          } else {
            const int which = e >> 10, h = (e >> 6) & 15, d = e & 63;
            const int bb = row >> 11, s = row & 2047;
            ((u16*)Cout)[(size_t)which * 4194304 +
                         (((size_t)(bb * 16 + h) * 2048 + s) << 6) + d] = f2bf(v);
          }
        }
      }
    }
  }
}

// ---------------- attn kernel 1: stats + O (single pass, no stores in loop) ------------
// grid: 1024 (XCD-chunked) = bh(32) x qtile(32). 4 waves x 16 q. K+V dbuf (32KB) + Pl 8KB
// -> 4 blocks/CU. Fixed-M0 softmax => O accumulates UNNORMALIZED in one pass; scaled by
// 1/lsum at the end. Writes O (bf16) + rl (f32 per q-row). MASKS ISSUED FIRST each round
// so the compiler's mask-use waitcnt does NOT drain the stage prefetch (FIFO vmcnt).
__global__ __launch_bounds__(256, 4) void attn_o(const u16* __restrict__ Q,
                                                 const u16* __restrict__ Kg,
                                                 const u16* __restrict__ Vtg,
                                                 const int* __restrict__ mask,
                                                 float* __restrict__ rlg,
                                                 u16* __restrict__ Og) {
  __shared__ u16 Ks[2][4096];
  __shared__ u16 Vs[2][4096];
  __shared__ u16 Pl[4][1024];  // per-wave [16 q][64 t] bf16, XOR-swizzled (lr&7)<<4
  const int L = ((int)blockIdx.x & 7) * 128 + ((int)blockIdx.x >> 3);
  const int bh = L >> 5, qt = L & 31;
  const int b = bh >> 4, h = bh & 15;
  const int tid = threadIdx.x;
  const int w = tid >> 6, lane = tid & 63;
  const int lr = lane & 15, lg = lane >> 4;
  const int srow0 = qt * 64 + w * 16;
  const float C2 = 0.18033688011112042f;  // log2(e)/8
  const float M2 = 11.541560327111707f;   // 8*log2(e)

  const u16* qrow = Q + ((size_t)bh * 2048 + srow0 + lr) * 64;
  const bf16x8 qf0 = *(const bf16x8*)(qrow + lg * 8);
  const bf16x8 qf1 = *(const bf16x8*)(qrow + 32 + lg * 8);
  const int* mrow = mask + b * 2048;

  auto stageK = [&](int kt, u16* dst) {
    const u16* g = Kg + (size_t)bh * 131072 + (size_t)kt * 4096;
#pragma unroll
    for (int iss = 0; iss < 2; ++iss) {
      const int o = iss * 256 + tid;
      const int row = o >> 3, c = o & 7;  // pre-swizzled source, linear LDS dest
      gload_lds16(g + row * 64 + ((c ^ (row & 7)) << 3), dst + (iss * 256 + w * 64) * 8);
    }
  };
  auto stageV = [&](int kt, u16* dst) {
    const u16* g = Vtg + (size_t)bh * 131072 + kt * 64;  // [d][t] rows, stride 2048
#pragma unroll
    for (int iss = 0; iss < 2; ++iss) {
      const int o = iss * 256 + tid;
      const int row = o >> 3, c = o & 7;
      gload_lds16(g + (size_t)row * 2048 + ((c ^ (row & 7)) << 3),
                  dst + (iss * 256 + w * 64) * 8);
    }
  };

  float lsum = 0.f;
  f32x4 oacc[4];
  const f32x4 z4 = {0.f, 0.f, 0.f, 0.f};
#pragma unroll
  for (int n = 0; n < 4; ++n) oacc[n] = z4;

  char* plw = (char*)&Pl[w][0];
  const int pswz = (lr & 7) << 4;

  stageK(0, &Ks[0][0]);
  stageV(0, &Vs[0][0]);
  WAITV(0);
  sbar();
  for (int t = 0; t < 32; ++t) {
    const int cur = t & 1;
    // masks FIRST (so later stage ops are newer in the vmcnt FIFO)
    int4 mv[4];
#pragma unroll
    for (int n = 0; n < 4; ++n) mv[n] = *(const int4*)&mrow[t * 64 + n * 16 + lg * 4];
    if (t + 1 < 32) {
      stageK(t + 1, &Ks[cur ^ 1][0]);
      stageV(t + 1, &Vs[cur ^ 1][0]);
    }
    // QK
    f32x4 sc[4];
    __builtin_amdgcn_s_setprio(1);
#pragma unroll
    for (int n = 0; n < 4; ++n) {
      const int tr = n * 16 + lr;
      const bf16x8 k0 = *(const bf16x8*)&Ks[cur][tr * 64 + ((lg ^ (tr & 7)) << 3)];
      const bf16x8 k1 = *(const bf16x8*)&Ks[cur][tr * 64 + (((lg + 4) ^ (tr & 7)) << 3)];
      f32x4 s = z4;
      s = __builtin_amdgcn_mfma_f32_16x16x32_bf16(k0, qf0, s, 0, 0, 0);
      s = __builtin_amdgcn_mfma_f32_16x16x32_bf16(k1, qf1, s, 0, 0, 0);
      sc[n] = s;
    }
    __builtin_amdgcn_s_setprio(0);
    // exp + lsum + P transpose
#pragma unroll
    for (int n = 0; n < 4; ++n) {
      f32x4 p;
      p[0] = (mv[n].x == 0) ? 0.f : fexp2(fmaf(sc[n][0], C2, -M2));
      p[1] = (mv[n].y == 0) ? 0.f : fexp2(fmaf(sc[n][1], C2, -M2));
      p[2] = (mv[n].z == 0) ? 0.f : fexp2(fmaf(sc[n][2], C2, -M2));
      p[3] = (mv[n].w == 0) ? 0.f : fexp2(fmaf(sc[n][3], C2, -M2));
      lsum += (p[0] + p[1]) + (p[2] + p[3]);
      uint2 pw;
      pw.x = cvtpk(p[0], p[1]);
      pw.y = cvtpk(p[2], p[3]);
      *(uint2*)(plw + (lr * 128 + ((n * 32 + lg * 8) ^ pswz))) = pw;
    }
    const bf16x8 pf0 = *(const bf16x8*)(plw + (lr * 128 + ((lg * 16) ^ pswz)));
    const bf16x8 pf1 = *(const bf16x8*)(plw + (lr * 128 + ((64 + lg * 16) ^ pswz)));
    // PV (unnormalized)
    __builtin_amdgcn_s_setprio(1);
#pragma unroll
    for (int n = 0; n < 4; ++n) {
      const int dr = n * 16 + lr;
      const bf16x8 v0 = *(const bf16x8*)&Vs[cur][dr * 64 + ((lg ^ (dr & 7)) << 3)];
      const bf16x8 v1 = *(const bf16x8*)&Vs[cur][dr * 64 + (((lg + 4) ^ (dr & 7)) << 3)];
      oacc[n] = __builtin_amdgcn_mfma_f32_16x16x32_bf16(pf0, v0, oacc[n], 0, 0, 0);
      oacc[n] = __builtin_amdgcn_mfma_f32_16x16x32_bf16(pf1, v1, oacc[n], 0, 0, 0);
    }
    __builtin_amdgcn_s_setprio(0);
    if (t + 1 < 32) {
      WAITV(0);  // only stage(t+1) outstanding here (masks landed mid-body)
      sbar();
    }
  }

  // merge lsum across the 4 copies of each q-row; rl uniform over lg
  lsum += __shfl_xor(lsum, 16);
  lsum += __shfl_xor(lsum, 32);
  const float rl = 1.0f / lsum;
  if (lg == 0) rlg[bh * 2048 + srow0 + lr] = rl;
  // oacc rows are q = srow0 + lg*4 + r -> fetch matching rl via in-wave shuffle
  float rlq[4];
#pragma unroll
  for (int r = 0; r < 4; ++r) rlq[r] = __shfl(rl, lg * 4 + r);
#pragma unroll
  for (int n = 0; n < 4; ++n)
#pragma unroll
    for (int r = 0; r < 4; ++r) {
      const int s = srow0 + lg * 4 + r;
      Og[((size_t)(b * 2048 + s)) * 1024 + h * 64 + n * 16 + lr] = f2bf(oacc[n][r] * rlq[r]);
    }
}

// ---------------- attn kernel 2: weights (write-BW-bound, lean) ----------------
// grid: 1024 (XCD-chunked) = bh(32) x qtile(32). 4 waves x 16 q (q = srow0+lr per lane).
// K staged in 128-t chunks (2x16KB ring, depth-1), 16 rounds. Per round: 8 int4 masks
// (FIRST), stage next chunk, 16 QK MFMA, 32 exp, x rl, 8 NT f32x4 stores. WAITV(8)
// leaves this round's stores in flight; only the chunk prefetch is drained.
__global__ __launch_bounds__(256, 4) void attn_w(const u16* __restrict__ Q,
                                                 const u16* __restrict__ Kg,
                                                 const int* __restrict__ mask,
                                                 const float* __restrict__ rlg,
                                                 float* __restrict__ Wout) {
  __shared__ u16 Kc[2][8192];  // 16KB per chunk: 128 t-rows x 64 d
  const int L = ((int)blockIdx.x & 7) * 128 + ((int)blockIdx.x >> 3);
  const int bh = L >> 5, qt = L & 31;
  const int b = bh >> 4;
  const int tid = threadIdx.x;
  const int w = tid >> 6, lane = tid & 63;
  const int lr = lane & 15, lg = lane >> 4;
  const int srow0 = qt * 64 + w * 16;
  const float C2 = 0.18033688011112042f;  // log2(e)/8
  const float M2 = 11.541560327111707f;   // 8*log2(e)

  const u16* qrow = Q + ((size_t)bh * 2048 + srow0 + lr) * 64;
  const bf16x8 qf0 = *(const bf16x8*)(qrow + lg * 8);
  const bf16x8 qf1 = *(const bf16x8*)(qrow + 32 + lg * 8);
  const int* mrow = mask + b * 2048;
  const float rl = rlg[bh * 2048 + srow0 + lr];
  float* wrow = Wout + ((size_t)bh * 2048 + srow0 + lr) * 2048;

  auto stageC = [&](int ch, u16* dst) {  // 16KB, 4 gload_lds/thread
    const u16* g = Kg + (size_t)bh * 131072 + (size_t)ch * 8192;
#pragma unroll
    for (int iss = 0; iss < 4; ++iss) {
      const int o = iss * 256 + tid;
      const int row = o >> 3, c = o & 7;
      gload_lds16(g + row * 64 + ((c ^ (row & 7)) << 3), dst + (iss * 256 + w * 64) * 8);
    }
  };

  stageC(0, &Kc[0][0]);
  WAITV(0);
  sbar();
  for (int r = 0; r < 16; ++r) {
    const int cur = r & 1;
    // masks FIRST
    int4 mv[8];
#pragma unroll
    for (int n = 0; n < 8; ++n) mv[n] = *(const int4*)&mrow[r * 128 + n * 16 + lg * 4];
    if (r + 1 < 16) stageC(r + 1, &Kc[cur ^ 1][0]);
    f32x4 sc[8];
    __builtin_amdgcn_s_setprio(1);
#pragma unroll
    for (int n = 0; n < 8; ++n) {
      const int tr = n * 16 + lr;
      const bf16x8 k0 = *(const bf16x8*)&Kc[cur][tr * 64 + ((lg ^ (tr & 7)) << 3)];
      const bf16x8 k1 = *(const bf16x8*)&Kc[cur][tr * 64 + (((lg + 4) ^ (tr & 7)) << 3)];
      f32x4 s = {0.f, 0.f, 0.f, 0.f};
      s = __builtin_amdgcn_mfma_f32_16x16x32_bf16(k0, qf0, s, 0, 0, 0);
      s = __builtin_amdgcn_mfma_f32_16x16x32_bf16(k1, qf1, s, 0, 0, 0);
      sc[n] = s;
    }
    __builtin_amdgcn_s_setprio(0);
#pragma unroll
    for (int n = 0; n < 8; ++n) {
      f32x4 wv;
      wv[0] = (mv[n].x == 0) ? 0.f : fexp2(fmaf(sc[n][0], C2, -M2)) * rl;
      wv[1] = (mv[n].y == 0) ? 0.f : fexp2(fmaf(sc[n][1], C2, -M2)) * rl;
      wv[2] = (mv[n].z == 0) ? 0.f : fexp2(fmaf(sc[n][2], C2, -M2)) * rl;
      wv[3] = (mv[n].w == 0) ? 0.f : fexp2(fmaf(sc[n][3], C2, -M2)) * rl;
      __builtin_nontemporal_store(wv, (f32x4*)&wrow[r * 128 + n * 16 + lg * 4]);
    }
    if (r + 1 < 16) {
      WAITV(8);  // drain chunk prefetch; keep this round's 8 stores in flight
      sbar();
    }
  }
}

// ---------------- launch ----------------
extern "C" void kernel_launch(void* const* d_in, const int* in_sizes, int n_in,
                              void* d_out, int out_size, void* d_ws, size_t ws_size,
                              hipStream_t stream) {
  const float* x     = (const float*)d_in[0];
  const int*   mask  = (const int*)d_in[1];
  const float* qkv_w = (const float*)d_in[2];
  const float* qkv_b = (const float*)d_in[3];
  const float* wo_w  = (const float*)d_in[4];
  const float* wo_b  = (const float*)d_in[5];
  float* out = (float*)d_out;

  char* ws = (char*)d_ws;
  u16* xb   = (u16*)(ws);                          // 4096x1024
  u16* qwb  = (u16*)(ws + (8u << 20));             // 3072x1024
  u16* wob  = (u16*)(ws + (14u << 20));            // 1024x1024
  u16* qkvb = (u16*)(ws + (16u << 20));            // Q,K: [bh][s][64] bf16
  float* rlb = (float*)(ws + (16u << 20) + 16777216);  // 64K f32 in unused V slot
  u16* vt   = (u16*)(ws + (40u << 20));            // [bh][64][2048] bf16 (QKV epi writes)
  u16* ob   = (u16*)(ws + (48u << 20));            // attn out [4096][1024] bf16

  cvt3<<<8192, 256, 0, stream>>>(x, xb, qkv_w, qwb, wo_w, wob);
  gemm_bt<1, 128, 128><<<768, 256, 0, stream>>>(xb, qwb, qkv_b, qkvb, vt, 4096, 3072, 1024);
  attn_o<<<1024, 256, 0, stream>>>(qkvb, qkvb + 4194304, vt, mask, rlb, ob);
  attn_w<<<1024, 256, 0, stream>>>(qkvb, qkvb + 4194304, mask, rlb, out + 4194304);
  gemm_bt<0, 128, 64><<<512, 256, 0, stream>>>(ob, wob, wo_b, out, nullptr, 4096, 1024, 1024);
}

// Round 10
// 201.581 us; speedup vs baseline: 1.4666x; 1.4666x over previous
//
#include <hip/hip_runtime.h>
#include <cstdint>
#include <cstddef>

typedef unsigned short u16;
typedef __attribute__((ext_vector_type(8))) short bf16x8;
typedef __attribute__((ext_vector_type(4))) float f32x4;

#define DEV static __device__ __forceinline__

DEV void gload_lds16(const void* g, void* l) {
  __builtin_amdgcn_global_load_lds((const __attribute__((address_space(1))) void*)g,
                                   (__attribute__((address_space(3))) void*)l, 16, 0, 0);
}

DEV u16 f2bf(float f) {  // RNE fp32 -> bf16 (finite inputs)
  unsigned x = __float_as_uint(f);
  return (u16)((x + 0x7FFFu + ((x >> 16) & 1u)) >> 16);
}

DEV unsigned cvtpk(float lo, float hi) {  // bf16(lo) in [15:0], bf16(hi) in [31:16]
  unsigned r;
  asm("v_cvt_pk_bf16_f32 %0, %1, %2" : "=v"(r) : "v"(lo), "v"(hi));
  return r;
}

#if __has_builtin(__builtin_amdgcn_exp2f)
DEV float fexp2(float x) { return __builtin_amdgcn_exp2f(x); }
#else
DEV float fexp2(float x) { return exp2f(x); }
#endif

// counted vmcnt wait + scheduling fence (rule #18)
#define WAITV(n)                                                   \
  do {                                                             \
    asm volatile("s_waitcnt vmcnt(" #n ")" ::: "memory");          \
    __builtin_amdgcn_sched_barrier(0);                             \
  } while (0)

DEV void sbar() {
  __builtin_amdgcn_sched_barrier(0);
  __builtin_amdgcn_s_barrier();
  __builtin_amdgcn_sched_barrier(0);
}

// ---------------- fp32 -> bf16 convert (3 buffers) + mask bit-pack ----------------
__global__ __launch_bounds__(256) void cvt3(const float* __restrict__ a, u16* __restrict__ da,
                                            const float* __restrict__ b, u16* __restrict__ db,
                                            const float* __restrict__ c, u16* __restrict__ dc,
                                            const int* __restrict__ mask,
                                            unsigned* __restrict__ mpack) {
  int bid = blockIdx.x;
  if (bid == 8192) {  // pack mask[2][2048] -> mpack[2][64] bitmaps
    const int j = threadIdx.x;
    if (j < 128) {
      const int* mb = mask + (j >> 6) * 2048 + (j & 63) * 32;
      unsigned bits = 0;
      for (int k = 0; k < 32; ++k) bits |= (mb[k] != 0 ? 1u : 0u) << k;
      mpack[j] = bits;
    }
    return;
  }
  const float* s;
  u16* d;
  int base;
  if (bid < 4096) { s = a; d = da; base = bid; }
  else if (bid < 7168) { s = b; d = db; base = bid - 4096; }
  else { s = c; d = dc; base = bid - 7168; }
  const int i = (base * 256 + (int)threadIdx.x) * 4;
  float4 v = *(const float4*)(s + i);
  uint2 p;
  p.x = (unsigned)f2bf(v.x) | ((unsigned)f2bf(v.y) << 16);
  p.y = (unsigned)f2bf(v.z) | ((unsigned)f2bf(v.w) << 16);
  *(uint2*)(d + i) = p;
}

// ---------------- GEMM: C = A * B^T (+bias) ----------------
// A[M][K] bf16 row-major, Bm[N][K] bf16 row-major.
// EPI 0: Cout = float[M][N], v + bias[e]
// EPI 1: QKV scatter: Q,K -> [which][b*16+h][s][d] bf16; V -> Vt[b*16+h][d][s] (transposed)
template <int EPI, int BM, int BN>
__global__ __launch_bounds__(256) void gemm_bt(const u16* __restrict__ A,
                                               const u16* __restrict__ Bm,
                                               const float* __restrict__ bias,
                                               void* __restrict__ Cout,
                                               u16* __restrict__ Vt,
                                               int M, int N, int K) {
  __shared__ u16 As[2][BM * 32];
  __shared__ u16 Bs[2][BN * 32];
  constexpr int MT = BM / 32, NT = BN / 32;
  const int cpx = (int)gridDim.x >> 3;
  const int bid = ((int)blockIdx.x & 7) * cpx + ((int)blockIdx.x >> 3);  // XCD chunking
  const int nb = N / BN;
  const int m0 = (bid / nb) * BM;
  const int n0 = (bid % nb) * BN;
  const int tid = threadIdx.x;
  const int w = tid >> 6, lane = tid & 63;
  const int wm = (w >> 1) * (BM / 2), wn = (w & 1) * (BN / 2);
  const int lr = lane & 15, lg = lane >> 4;

  f32x4 acc[MT][NT];
  const f32x4 z4 = {0.f, 0.f, 0.f, 0.f};
#pragma unroll
  for (int m = 0; m < MT; ++m)
#pragma unroll
    for (int n = 0; n < NT; ++n) acc[m][n] = z4;

  auto stage = [&](int ks, int buf) {
    const int k0 = ks << 5;
#pragma unroll
    for (int i = 0; i < BM * 4 / 256; ++i) {
      const int o = i * 256 + tid;
      const int row = o >> 2, c = o & 3;
      gload_lds16(A + (size_t)(m0 + row) * K + k0 + c * 8, &As[buf][(i * 256 + w * 64) * 8]);
    }
#pragma unroll
    for (int i = 0; i < BN * 4 / 256; ++i) {
      const int o = i * 256 + tid;
      const int row = o >> 2, c = o & 3;
      gload_lds16(Bm + (size_t)(n0 + row) * K + k0 + c * 8, &Bs[buf][(i * 256 + w * 64) * 8]);
    }
  };

  const int nk = K >> 5;
  stage(0, 0);
  __syncthreads();
  for (int ks = 0; ks < nk; ++ks) {
    const int cur = ks & 1;
    if (ks + 1 < nk) stage(ks + 1, cur ^ 1);
    bf16x8 af[MT], bfr[NT];
#pragma unroll
    for (int m = 0; m < MT; ++m)
      af[m] = *(const bf16x8*)&As[cur][(wm + m * 16 + lr) * 32 + lg * 8];
#pragma unroll
    for (int n = 0; n < NT; ++n)
      bfr[n] = *(const bf16x8*)&Bs[cur][(wn + n * 16 + lr) * 32 + lg * 8];
    __builtin_amdgcn_s_setprio(1);
#pragma unroll
    for (int m = 0; m < MT; ++m)
#pragma unroll
      for (int n = 0; n < NT; ++n)
        acc[m][n] = __builtin_amdgcn_mfma_f32_16x16x32_bf16(af[m], bfr[n], acc[m][n], 0, 0, 0);
    __builtin_amdgcn_s_setprio(0);
    __syncthreads();
  }

#pragma unroll
  for (int n = 0; n < NT; ++n) {
    const int e = n0 + wn + n * 16 + lr;
    const float bv = bias[e];
    if (EPI == 1 && (e >> 10) == 2) {
      // V: write transposed [bh][d][s], 4 consecutive s packed per store
      const int h = (e >> 6) & 15, d = e & 63;
#pragma unroll
      for (int m = 0; m < MT; ++m) {
        const int row0 = m0 + wm + m * 16 + lg * 4;
        const int bb = row0 >> 11, s0 = row0 & 2047;
        uint2 pv;
        pv.x = cvtpk(acc[m][n][0] + bv, acc[m][n][1] + bv);
        pv.y = cvtpk(acc[m][n][2] + bv, acc[m][n][3] + bv);
        *(uint2*)(Vt + (size_t)(bb * 16 + h) * 131072 + (size_t)d * 2048 + s0) = pv;
      }
    } else {
#pragma unroll
      for (int m = 0; m < MT; ++m) {
#pragma unroll
        for (int r = 0; r < 4; ++r) {
          const int row = m0 + wm + m * 16 + lg * 4 + r;  // D: col=lane&15, row=(lane>>4)*4+r
          const float v = acc[m][n][r] + bv;
          if (EPI == 0) {
            ((float*)Cout)[(size_t)row * N + e] = v;
          } else {
            const int which = e >> 10, h = (e >> 6) & 15, d = e & 63;
            const int bb = row >> 11, s = row & 2047;
            ((u16*)Cout)[(size_t)which * 4194304 +
                         (((size_t)(bb * 16 + h) * 2048 + s) << 6) + d] = f2bf(v);
          }
        }
      }
    }
  }
}

// ---------------- fused attention: R6 structure + coalesced W stores + bitmask ----------
// grid: 1024 (XCD-chunked) = bh(32) x qtile(32). 4 waves x 16 q. Fixed-M0 softmax.
// Pass 1: K-only 3-buffer ring depth-2, WAITV(2). Pass 2: K+V dbuf depth-1, WAITV(4);
// weight stores go through a per-wave 2KB f32 LDS transpose (Pf) so each store instr
// covers 8 rows x 128B CONTIGUOUS (full lines) -- fixes the 64B-segment NT-write BW loss.
// PV bf16 A-frags derived from Pf via cvt_pk (no separate Pl). Mask via scalar-loaded
// bitmaps (lgkmcnt, outside the vmcnt FIFO) + all-ones fast path.
__global__ __launch_bounds__(256, 4) void attn(const u16* __restrict__ Q,
                                               const u16* __restrict__ Kg,
                                               const u16* __restrict__ Vtg,
                                               const unsigned* __restrict__ mpack,
                                               float* __restrict__ Wout,
                                               u16* __restrict__ Og) {
  __shared__ u16 Ks[2][4096];
  __shared__ u16 Vs[2][4096];
  __shared__ float Pf[4][512];  // per-wave [16 q][32 t] f32, XOR-swizzled, reused per half
  const int L = ((int)blockIdx.x & 7) * 128 + ((int)blockIdx.x >> 3);  // XCD chunking
  const int bh = L >> 5, qt = L & 31;
  const int b = bh >> 4, h = bh & 15;
  const int tid = threadIdx.x;
  const int w = tid >> 6, lane = tid & 63;
  const int lr = lane & 15, lg = lane >> 4;
  const int srow0 = qt * 64 + w * 16;
  const float C2 = 0.18033688011112042f;  // log2(e)/8
  const float M2 = 11.541560327111707f;   // 8*log2(e)

  const u16* qrow = Q + ((size_t)bh * 2048 + srow0 + lr) * 64;
  const bf16x8 qf0 = *(const bf16x8*)(qrow + lg * 8);
  const bf16x8 qf1 = *(const bf16x8*)(qrow + 32 + lg * 8);
  const unsigned* mpk = mpack + b * 64;

  auto stageK = [&](int kt, u16* dst) {  // 2 gload_lds/thread
    const u16* g = Kg + (size_t)bh * 131072 + (size_t)kt * 4096;
#pragma unroll
    for (int iss = 0; iss < 2; ++iss) {
      const int o = iss * 256 + tid;
      const int row = o >> 3, c = o & 7;  // pre-swizzled source, linear LDS dest
      gload_lds16(g + row * 64 + ((c ^ (row & 7)) << 3), dst + (iss * 256 + w * 64) * 8);
    }
  };
  auto stageV = [&](int kt, u16* dst) {  // 2 gload_lds/thread
    const u16* g = Vtg + (size_t)bh * 131072 + kt * 64;  // [d][t] rows, stride 2048
#pragma unroll
    for (int iss = 0; iss < 2; ++iss) {
      const int o = iss * 256 + tid;
      const int row = o >> 3, c = o & 7;
      gload_lds16(g + (size_t)row * 2048 + ((c ^ (row & 7)) << 3),
                  dst + (iss * 256 + w * 64) * 8);
    }
  };
  // QK scores for one 64-t tile from LDS buffer kb
  auto qk = [&](const u16* kb, f32x4* sc) {
    const f32x4 z4 = {0.f, 0.f, 0.f, 0.f};
    __builtin_amdgcn_s_setprio(1);
#pragma unroll
    for (int n = 0; n < 4; ++n) {
      const int tr = n * 16 + lr;
      const bf16x8 k0 = *(const bf16x8*)&kb[tr * 64 + ((lg ^ (tr & 7)) << 3)];
      const bf16x8 k1 = *(const bf16x8*)&kb[tr * 64 + (((lg + 4) ^ (tr & 7)) << 3)];
      f32x4 s = z4;
      s = __builtin_amdgcn_mfma_f32_16x16x32_bf16(k0, qf0, s, 0, 0, 0);
      s = __builtin_amdgcn_mfma_f32_16x16x32_bf16(k1, qf1, s, 0, 0, 0);
      sc[n] = s;
    }
    __builtin_amdgcn_s_setprio(0);
  };

  // ---- pass 1: per-lane denominator; K ring {Ks[0],Ks[1],Vs[0]}, depth-2 ----
  stageK(0, &Ks[0][0]);
  stageK(1, &Ks[1][0]);
  WAITV(2);
  sbar();
  float lsum = 0.f;
  int cur3 = 0, stg3 = 2;
  for (int t = 0; t < 32; ++t) {
    u16* curb = (cur3 == 0) ? &Ks[0][0] : ((cur3 == 1) ? &Ks[1][0] : &Vs[0][0]);
    const unsigned mx = mpk[t * 2], my = mpk[t * 2 + 1];  // scalar loads (lgkmcnt)
    if (t + 2 < 32) {
      u16* stb = (stg3 == 0) ? &Ks[0][0] : ((stg3 == 1) ? &Ks[1][0] : &Vs[0][0]);
      stageK(t + 2, stb);
    }
    f32x4 sc[4];
    qk(curb, sc);
    f32x4 p[4];
#pragma unroll
    for (int n = 0; n < 4; ++n)
#pragma unroll
      for (int r = 0; r < 4; ++r) p[n][r] = fexp2(fmaf(sc[n][r], C2, -M2));
    if ((mx & my) != 0xFFFFFFFFu) {  // wave-uniform slow path
#pragma unroll
      for (int n = 0; n < 4; ++n) {
        const unsigned wsel = (n < 2) ? mx : my;
#pragma unroll
        for (int r = 0; r < 4; ++r) {
          const unsigned bit = (wsel >> ((n & 1) * 16 + lg * 4 + r)) & 1u;
          p[n][r] = bit ? p[n][r] : 0.f;
        }
      }
    }
#pragma unroll
    for (int n = 0; n < 4; ++n) lsum += (p[n][0] + p[n][1]) + (p[n][2] + p[n][3]);
    if (t + 1 < 32) {
      if (t + 2 < 32) {
        WAITV(2);  // stage(t+1) done; stage(t+2) stays in flight
      } else {
        WAITV(0);
      }
      sbar();
    }
    cur3 = (cur3 == 2) ? 0 : cur3 + 1;
    stg3 = (stg3 == 2) ? 0 : stg3 + 1;
  }
  lsum += __shfl_xor(lsum, 16);
  lsum += __shfl_xor(lsum, 32);
  const float rl = 1.0f / lsum;

  // ---- pass 2: weights + PV ----
  sbar();  // all waves out of pass-1 reads
  f32x4 oacc[4];
  const f32x4 z4 = {0.f, 0.f, 0.f, 0.f};
#pragma unroll
  for (int n = 0; n < 4; ++n) oacc[n] = z4;

  float* Wb = Wout + (size_t)bh * 2048 * 2048;  // + row*2048 + t
  char* pfw = (char*)&Pf[w][0];
  const int sw = (lr & 7) << 4;
  const int ql0 = lane >> 3, ch = lane & 7;  // coalesced-store lane roles

  stageK(0, &Ks[0][0]);
  stageV(0, &Vs[0][0]);
  WAITV(0);
  sbar();
  for (int t = 0; t < 32; ++t) {
    const int cur = t & 1;
    const unsigned mx = mpk[t * 2], my = mpk[t * 2 + 1];
    if (t + 1 < 32) {
      stageK(t + 1, &Ks[cur ^ 1][0]);
      stageV(t + 1, &Vs[cur ^ 1][0]);
    }
    f32x4 sc[4];
    qk(&Ks[cur][0], sc);
    f32x4 wv[4];
#pragma unroll
    for (int n = 0; n < 4; ++n)
#pragma unroll
      for (int r = 0; r < 4; ++r) wv[n][r] = fexp2(fmaf(sc[n][r], C2, -M2)) * rl;
    if ((mx & my) != 0xFFFFFFFFu) {
#pragma unroll
      for (int n = 0; n < 4; ++n) {
        const unsigned wsel = (n < 2) ? mx : my;
#pragma unroll
        for (int r = 0; r < 4; ++r) {
          const unsigned bit = (wsel >> ((n & 1) * 16 + lg * 4 + r)) & 1u;
          wv[n][r] = bit ? wv[n][r] : 0.f;
        }
      }
    }
#pragma unroll
    for (int hh = 0; hh < 2; ++hh) {  // 32-t halves through the 2KB Pf transpose
      // in: lane(lr,lg) owns w[q=lr][tl=(n&1)*16+lg*4 ..+3]
      *(f32x4*)(pfw + (lr * 128 + ((lg * 16) ^ sw))) = wv[2 * hh];
      *(f32x4*)(pfw + (lr * 128 + ((64 + lg * 16) ^ sw))) = wv[2 * hh + 1];
      // out (coalesced): instr s2 covers 8 rows x 128B contiguous
#pragma unroll
      for (int s2 = 0; s2 < 2; ++s2) {
        const int ql = s2 * 8 + ql0;
        const f32x4 rv = *(const f32x4*)(pfw + (ql * 128 + ((ch * 16) ^ ((ql & 7) << 4))));
        __builtin_nontemporal_store(
            rv, (f32x4*)(Wb + (size_t)(srow0 + ql) * 2048 + t * 64 + hh * 32 + ch * 4));
      }
      // PV A-frag: w[q=lr][tl=lg*8..+7] -> bf16
      const f32x4 a0 = *(const f32x4*)(pfw + (lr * 128 + ((lg * 32) ^ sw)));
      const f32x4 a1 = *(const f32x4*)(pfw + (lr * 128 + ((lg * 32 + 16) ^ sw)));
      int4 pk4;
      pk4.x = cvtpk(a0[0], a0[1]);
      pk4.y = cvtpk(a0[2], a0[3]);
      pk4.z = cvtpk(a1[0], a1[1]);
      pk4.w = cvtpk(a1[2], a1[3]);
      const bf16x8 pfr = *(const bf16x8*)&pk4;
      __builtin_amdgcn_s_setprio(1);
#pragma unroll
      for (int n = 0; n < 4; ++n) {
        const int dr = n * 16 + lr;
        const bf16x8 vf = *(const bf16x8*)&Vs[cur][dr * 64 + (((lg + hh * 4) ^ (dr & 7)) << 3)];
        oacc[n] = __builtin_amdgcn_mfma_f32_16x16x32_bf16(pfr, vf, oacc[n], 0, 0, 0);
      }
      __builtin_amdgcn_s_setprio(0);
    }
    if (t + 1 < 32) {
      WAITV(4);  // stage(t+1) done; this round's 4 NT stores stay in flight
      sbar();
    }
  }

  // O: lane holds O[q = srow0 + lg*4 + r][d = n*16 + lr]
#pragma unroll
  for (int n = 0; n < 4; ++n)
#pragma unroll
    for (int r = 0; r < 4; ++r) {
      const int s = srow0 + lg * 4 + r;
      Og[((size_t)(b * 2048 + s)) * 1024 + h * 64 + n * 16 + lr] = f2bf(oacc[n][r]);
    }
}

// ---------------- launch ----------------
extern "C" void kernel_launch(void* const* d_in, const int* in_sizes, int n_in,
                              void* d_out, int out_size, void* d_ws, size_t ws_size,
                              hipStream_t stream) {
  const float* x     = (const float*)d_in[0];
  const int*   mask  = (const int*)d_in[1];
  const float* qkv_w = (const float*)d_in[2];
  const float* qkv_b = (const float*)d_in[3];
  const float* wo_w  = (const float*)d_in[4];
  const float* wo_b  = (const float*)d_in[5];
  float* out = (float*)d_out;

  char* ws = (char*)d_ws;
  u16* xb   = (u16*)(ws);                          // 4096x1024
  u16* qwb  = (u16*)(ws + (8u << 20));             // 3072x1024
  u16* wob  = (u16*)(ws + (14u << 20));            // 1024x1024
  u16* qkvb = (u16*)(ws + (16u << 20));            // Q,K: [bh][s][64] bf16
  unsigned* mpack = (unsigned*)(ws + (16u << 20) + 16777216);  // 512B in unused V slot
  u16* vt   = (u16*)(ws + (40u << 20));            // [bh][64][2048] bf16 (QKV epi writes)
  u16* ob   = (u16*)(ws + (48u << 20));            // attn out [4096][1024] bf16

  cvt3<<<8193, 256, 0, stream>>>(x, xb, qkv_w, qwb, wo_w, wob, mask, mpack);
  gemm_bt<1, 128, 128><<<768, 256, 0, stream>>>(xb, qwb, qkv_b, qkvb, vt, 4096, 3072, 1024);
  attn<<<1024, 256, 0, stream>>>(qkvb, qkvb + 4194304, vt, mpack, out + 4194304, ob);
  gemm_bt<0, 128, 64><<<512, 256, 0, stream>>>(ob, wob, wo_b, out, nullptr, 4096, 1024, 1024);
}

// Round 11
// 199.114 us; speedup vs baseline: 1.4848x; 1.0124x over previous
//
#include <hip/hip_runtime.h>
#include <cstdint>
#include <cstddef>

typedef unsigned short u16;
typedef __attribute__((ext_vector_type(8))) short bf16x8;
typedef __attribute__((ext_vector_type(4))) float f32x4;

#define DEV static __device__ __forceinline__

DEV void gload_lds16(const void* g, void* l) {
  __builtin_amdgcn_global_load_lds((const __attribute__((address_space(1))) void*)g,
                                   (__attribute__((address_space(3))) void*)l, 16, 0, 0);
}

DEV u16 f2bf(float f) {  // RNE fp32 -> bf16 (finite inputs)
  unsigned x = __float_as_uint(f);
  return (u16)((x + 0x7FFFu + ((x >> 16) & 1u)) >> 16);
}

DEV unsigned cvtpk(float lo, float hi) {  // bf16(lo) in [15:0], bf16(hi) in [31:16]
  unsigned r;
  asm("v_cvt_pk_bf16_f32 %0, %1, %2" : "=v"(r) : "v"(lo), "v"(hi));
  return r;
}

#if __has_builtin(__builtin_amdgcn_exp2f)
DEV float fexp2(float x) { return __builtin_amdgcn_exp2f(x); }
#else
DEV float fexp2(float x) { return exp2f(x); }
#endif

// counted vmcnt wait + scheduling fence (rule #18)
#define WAITV(n)                                                   \
  do {                                                             \
    asm volatile("s_waitcnt vmcnt(" #n ")" ::: "memory");          \
    __builtin_amdgcn_sched_barrier(0);                             \
  } while (0)

DEV void sbar() {
  __builtin_amdgcn_sched_barrier(0);
  __builtin_amdgcn_s_barrier();
  __builtin_amdgcn_sched_barrier(0);
}

// ---------------- fp32 -> bf16 convert (3 buffers) + mask bit-pack ----------------
__global__ __launch_bounds__(256) void cvt3(const float* __restrict__ a, u16* __restrict__ da,
                                            const float* __restrict__ b, u16* __restrict__ db,
                                            const float* __restrict__ c, u16* __restrict__ dc,
                                            const int* __restrict__ mask,
                                            unsigned* __restrict__ mpack) {
  int bid = blockIdx.x;
  if (bid == 8192) {  // pack mask[2][2048] -> mpack[2][64] bitmaps
    const int j = threadIdx.x;
    if (j < 128) {
      const int* mb = mask + (j >> 6) * 2048 + (j & 63) * 32;
      unsigned bits = 0;
      for (int k = 0; k < 32; ++k) bits |= (mb[k] != 0 ? 1u : 0u) << k;
      mpack[j] = bits;
    }
    return;
  }
  const float* s;
  u16* d;
  int base;
  if (bid < 4096) { s = a; d = da; base = bid; }
  else if (bid < 7168) { s = b; d = db; base = bid - 4096; }
  else { s = c; d = dc; base = bid - 7168; }
  const int i = (base * 256 + (int)threadIdx.x) * 4;
  float4 v = *(const float4*)(s + i);
  uint2 p;
  p.x = (unsigned)f2bf(v.x) | ((unsigned)f2bf(v.y) << 16);
  p.y = (unsigned)f2bf(v.z) | ((unsigned)f2bf(v.w) << 16);
  *(uint2*)(d + i) = p;
}

// ---------------- GEMM: C = A * B^T (+bias) ----------------
// A[M][K] bf16 row-major, Bm[N][K] bf16 row-major.
// EPI 0: Cout = float[M][N], v + bias[e]
// EPI 1: QKV scatter: Q,K -> [which][b*16+h][s][d] bf16; V -> Vt[b*16+h][d][s] (transposed)
template <int EPI, int BM, int BN>
__global__ __launch_bounds__(256) void gemm_bt(const u16* __restrict__ A,
                                               const u16* __restrict__ Bm,
                                               const float* __restrict__ bias,
                                               void* __restrict__ Cout,
                                               u16* __restrict__ Vt,
                                               int M, int N, int K) {
  __shared__ u16 As[2][BM * 32];
  __shared__ u16 Bs[2][BN * 32];
  constexpr int MT = BM / 32, NT = BN / 32;
  const int cpx = (int)gridDim.x >> 3;
  const int bid = ((int)blockIdx.x & 7) * cpx + ((int)blockIdx.x >> 3);  // XCD chunking
  const int nb = N / BN;
  const int m0 = (bid / nb) * BM;
  const int n0 = (bid % nb) * BN;
  const int tid = threadIdx.x;
  const int w = tid >> 6, lane = tid & 63;
  const int wm = (w >> 1) * (BM / 2), wn = (w & 1) * (BN / 2);
  const int lr = lane & 15, lg = lane >> 4;

  f32x4 acc[MT][NT];
  const f32x4 z4 = {0.f, 0.f, 0.f, 0.f};
#pragma unroll
  for (int m = 0; m < MT; ++m)
#pragma unroll
    for (int n = 0; n < NT; ++n) acc[m][n] = z4;

  auto stage = [&](int ks, int buf) {
    const int k0 = ks << 5;
#pragma unroll
    for (int i = 0; i < BM * 4 / 256; ++i) {
      const int o = i * 256 + tid;
      const int row = o >> 2, c = o & 3;
      gload_lds16(A + (size_t)(m0 + row) * K + k0 + c * 8, &As[buf][(i * 256 + w * 64) * 8]);
    }
#pragma unroll
    for (int i = 0; i < BN * 4 / 256; ++i) {
      const int o = i * 256 + tid;
      const int row = o >> 2, c = o & 3;
      gload_lds16(Bm + (size_t)(n0 + row) * K + k0 + c * 8, &Bs[buf][(i * 256 + w * 64) * 8]);
    }
  };

  const int nk = K >> 5;
  stage(0, 0);
  __syncthreads();
  for (int ks = 0; ks < nk; ++ks) {
    const int cur = ks & 1;
    if (ks + 1 < nk) stage(ks + 1, cur ^ 1);
    bf16x8 af[MT], bfr[NT];
#pragma unroll
    for (int m = 0; m < MT; ++m)
      af[m] = *(const bf16x8*)&As[cur][(wm + m * 16 + lr) * 32 + lg * 8];
#pragma unroll
    for (int n = 0; n < NT; ++n)
      bfr[n] = *(const bf16x8*)&Bs[cur][(wn + n * 16 + lr) * 32 + lg * 8];
    __builtin_amdgcn_s_setprio(1);
#pragma unroll
    for (int m = 0; m < MT; ++m)
#pragma unroll
      for (int n = 0; n < NT; ++n)
        acc[m][n] = __builtin_amdgcn_mfma_f32_16x16x32_bf16(af[m], bfr[n], acc[m][n], 0, 0, 0);
    __builtin_amdgcn_s_setprio(0);
    __syncthreads();
  }

#pragma unroll
  for (int n = 0; n < NT; ++n) {
    const int e = n0 + wn + n * 16 + lr;
    const float bv = bias[e];
    if (EPI == 1 && (e >> 10) == 2) {
      // V: write transposed [bh][d][s], 4 consecutive s packed per store
      const int h = (e >> 6) & 15, d = e & 63;
#pragma unroll
      for (int m = 0; m < MT; ++m) {
        const int row0 = m0 + wm + m * 16 + lg * 4;
        const int bb = row0 >> 11, s0 = row0 & 2047;
        uint2 pv;
        pv.x = cvtpk(acc[m][n][0] + bv, acc[m][n][1] + bv);
        pv.y = cvtpk(acc[m][n][2] + bv, acc[m][n][3] + bv);
        *(uint2*)(Vt + (size_t)(bb * 16 + h) * 131072 + (size_t)d * 2048 + s0) = pv;
      }
    } else {
#pragma unroll
      for (int m = 0; m < MT; ++m) {
#pragma unroll
        for (int r = 0; r < 4; ++r) {
          const int row = m0 + wm + m * 16 + lg * 4 + r;  // D: col=lane&15, row=(lane>>4)*4+r
          const float v = acc[m][n][r] + bv;
          if (EPI == 0) {
            ((float*)Cout)[(size_t)row * N + e] = v;
          } else {
            const int which = e >> 10, h = (e >> 6) & 15, d = e & 63;
            const int bb = row >> 11, s = row & 2047;
            ((u16*)Cout)[(size_t)which * 4194304 +
                         (((size_t)(bb * 16 + h) * 2048 + s) << 6) + d] = f2bf(v);
          }
        }
      }
    }
  }
}

// ---------------- fused attention: chain-2 q-tiles, phase-overlapped ----------------
// grid: 512 (XCD-chunked) = bh(32) x qpair(16). 4 waves x 16 q per tile; each block owns
// TWO 64-q tiles (qa, qb). Loop A: pass1(qa), 128-t chunks, 16 rounds (lean). Loop B:
// pass2(qa) INTERLEAVED with pass1(qb) -- staged K feeds both QK^T (K frags read once).
// Loop C: pass2(qb). Write-active rounds: 64/80 (vs 64/128 unchained) -> write-engine
// duty 50%->80%. Coalesced weight stores via 2KB/wave Pf transpose; scalar bitmask;
// counted vmcnt (stores never drained in-loop). Fixed-M0 softmax.
__global__ __launch_bounds__(256, 2) void attn(const u16* __restrict__ Q,
                                               const u16* __restrict__ Kg,
                                               const u16* __restrict__ Vtg,
                                               const unsigned* __restrict__ mpack,
                                               float* __restrict__ Wout,
                                               u16* __restrict__ Og) {
  __shared__ u16 SM[16384];     // 32KB: loopA = 2x16KB chunk ring; loopB/C = Kdbuf|Vdbuf
  __shared__ float Pf[4][512];  // per-wave [16 q][32 t] f32, XOR-swizzled
  const int L = ((int)blockIdx.x & 7) * 64 + ((int)blockIdx.x >> 3);  // XCD chunking
  const int bh = L >> 4, pair = L & 15;
  const int b = bh >> 4, h = bh & 15;
  const int tid = threadIdx.x;
  const int w = tid >> 6, lane = tid & 63;
  const int lr = lane & 15, lg = lane >> 4;
  const int sr_a = pair * 128 + w * 16;  // qa rows; qb = +64
  const int sr_b = sr_a + 64;
  const float C2 = 0.18033688011112042f;  // log2(e)/8
  const float M2 = 11.541560327111707f;   // 8*log2(e)
  const f32x4 z4 = {0.f, 0.f, 0.f, 0.f};

  const u16* qra = Q + ((size_t)bh * 2048 + sr_a + lr) * 64;
  const u16* qrb = qra + 64 * 64;
  const bf16x8 qfa0 = *(const bf16x8*)(qra + lg * 8);
  const bf16x8 qfa1 = *(const bf16x8*)(qra + 32 + lg * 8);
  const bf16x8 qfb0 = *(const bf16x8*)(qrb + lg * 8);
  const bf16x8 qfb1 = *(const bf16x8*)(qrb + 32 + lg * 8);
  const unsigned* mpk = mpack + b * 64;

  auto stageC = [&](int ch, u16* dst) {  // 128 K rows (16KB), 4 gload_lds/thread
    const u16* g = Kg + (size_t)bh * 131072 + (size_t)ch * 8192;
#pragma unroll
    for (int iss = 0; iss < 4; ++iss) {
      const int o = iss * 256 + tid;
      const int row = o >> 3, c = o & 7;  // pre-swizzled source, linear LDS dest
      gload_lds16(g + row * 64 + ((c ^ (row & 7)) << 3), dst + (iss * 256 + w * 64) * 8);
    }
  };
  auto stageK = [&](int kt, u16* dst) {  // 64 K rows (8KB)
    const u16* g = Kg + (size_t)bh * 131072 + (size_t)kt * 4096;
#pragma unroll
    for (int iss = 0; iss < 2; ++iss) {
      const int o = iss * 256 + tid;
      const int row = o >> 3, c = o & 7;
      gload_lds16(g + row * 64 + ((c ^ (row & 7)) << 3), dst + (iss * 256 + w * 64) * 8);
    }
  };
  auto stageV = [&](int kt, u16* dst) {  // 64 Vt rows (8KB)
    const u16* g = Vtg + (size_t)bh * 131072 + kt * 64;  // [d][t] rows, stride 2048
#pragma unroll
    for (int iss = 0; iss < 2; ++iss) {
      const int o = iss * 256 + tid;
      const int row = o >> 3, c = o & 7;
      gload_lds16(g + (size_t)row * 2048 + ((c ^ (row & 7)) << 3),
                  dst + (iss * 256 + w * 64) * 8);
    }
  };
  // QK scores for one 64-t tile from LDS kb with given Q frags
  auto qk1 = [&](const u16* kb, const bf16x8& q0, const bf16x8& q1, f32x4* sc) {
    __builtin_amdgcn_s_setprio(1);
#pragma unroll
    for (int n = 0; n < 4; ++n) {
      const int tr = n * 16 + lr;
      const bf16x8 k0 = *(const bf16x8*)&kb[tr * 64 + ((lg ^ (tr & 7)) << 3)];
      const bf16x8 k1 = *(const bf16x8*)&kb[tr * 64 + (((lg + 4) ^ (tr & 7)) << 3)];
      f32x4 s = z4;
      s = __builtin_amdgcn_mfma_f32_16x16x32_bf16(k0, q0, s, 0, 0, 0);
      s = __builtin_amdgcn_mfma_f32_16x16x32_bf16(k1, q1, s, 0, 0, 0);
      sc[n] = s;
    }
    __builtin_amdgcn_s_setprio(0);
  };
  auto maskp = [&](unsigned mx, unsigned my, f32x4* p) {
    if ((mx & my) != 0xFFFFFFFFu) {
#pragma unroll
      for (int n = 0; n < 4; ++n) {
        const unsigned wsel = (n < 2) ? mx : my;
#pragma unroll
        for (int r = 0; r < 4; ++r) {
          const unsigned bit = (wsel >> ((n & 1) * 16 + lg * 4 + r)) & 1u;
          p[n][r] = bit ? p[n][r] : 0.f;
        }
      }
    }
  };

  char* pfw = (char*)&Pf[w][0];
  const int sw = (lr & 7) << 4;
  const int ql0 = lane >> 3, ch8 = lane & 7;  // coalesced-store lane roles

  // pass-2 round for one tile t (weights store + PV accum), given wv[] normalized
  auto p2tail = [&](int t, const u16* vb, f32x4* wv, float* Wb0, f32x4* oacc) {
#pragma unroll
    for (int hh = 0; hh < 2; ++hh) {
      *(f32x4*)(pfw + (lr * 128 + ((lg * 16) ^ sw))) = wv[2 * hh];
      *(f32x4*)(pfw + (lr * 128 + ((64 + lg * 16) ^ sw))) = wv[2 * hh + 1];
#pragma unroll
      for (int s2 = 0; s2 < 2; ++s2) {
        const int ql = s2 * 8 + ql0;
        const f32x4 rv = *(const f32x4*)(pfw + (ql * 128 + ((ch8 * 16) ^ ((ql & 7) << 4))));
        __builtin_nontemporal_store(
            rv, (f32x4*)(Wb0 + (size_t)ql * 2048 + t * 64 + hh * 32 + ch8 * 4));
      }
      const f32x4 a0 = *(const f32x4*)(pfw + (lr * 128 + ((lg * 32) ^ sw)));
      const f32x4 a1 = *(const f32x4*)(pfw + (lr * 128 + ((lg * 32 + 16) ^ sw)));
      int4 pk4;
      pk4.x = cvtpk(a0[0], a0[1]);
      pk4.y = cvtpk(a0[2], a0[3]);
      pk4.z = cvtpk(a1[0], a1[1]);
      pk4.w = cvtpk(a1[2], a1[3]);
      const bf16x8 pfr = *(const bf16x8*)&pk4;
      __builtin_amdgcn_s_setprio(1);
#pragma unroll
      for (int n = 0; n < 4; ++n) {
        const int dr = n * 16 + lr;
        const bf16x8 vf = *(const bf16x8*)&vb[dr * 64 + (((lg + hh * 4) ^ (dr & 7)) << 3)];
        oacc[n] = __builtin_amdgcn_mfma_f32_16x16x32_bf16(pfr, vf, oacc[n], 0, 0, 0);
      }
      __builtin_amdgcn_s_setprio(0);
    }
  };

  // ---- loop A: pass1(qa); 128-t chunk ring, 16 rounds ----
  float lsa = 0.f;
  stageC(0, &SM[0]);
  WAITV(0);
  sbar();
  for (int r = 0; r < 16; ++r) {
    const u16* cb = &SM[(r & 1) * 8192];
    const unsigned m0_ = mpk[r * 4], m1_ = mpk[r * 4 + 1];
    const unsigned m2_ = mpk[r * 4 + 2], m3_ = mpk[r * 4 + 3];
    if (r + 1 < 16) stageC(r + 1, &SM[((r + 1) & 1) * 8192]);
#pragma unroll
    for (int hh = 0; hh < 2; ++hh) {
      f32x4 sc[4];
      qk1(cb + hh * 4096, qfa0, qfa1, sc);
      f32x4 p[4];
#pragma unroll
      for (int n = 0; n < 4; ++n)
#pragma unroll
        for (int rr = 0; rr < 4; ++rr) p[n][rr] = fexp2(fmaf(sc[n][rr], C2, -M2));
      maskp(hh ? m2_ : m0_, hh ? m3_ : m1_, p);
#pragma unroll
      for (int n = 0; n < 4; ++n) lsa += (p[n][0] + p[n][1]) + (p[n][2] + p[n][3]);
    }
    if (r + 1 < 16) {
      WAITV(0);
      sbar();
    }
  }
  lsa += __shfl_xor(lsa, 16);
  lsa += __shfl_xor(lsa, 32);
  const float rl_a = 1.0f / lsa;
  sbar();  // all waves done with loop-A chunk reads

  // ---- loop B: pass2(qa) || pass1(qb); K+V dbuf, 32 rounds ----
  f32x4 oacc[4];
#pragma unroll
  for (int n = 0; n < 4; ++n) oacc[n] = z4;
  float lsb = 0.f;
  float* Wba = Wout + ((size_t)bh * 2048 + sr_a) * 2048;
  float* Wbb = Wout + ((size_t)bh * 2048 + sr_b) * 2048;

  stageK(0, &SM[0]);
  stageV(0, &SM[8192]);
  WAITV(0);
  sbar();
  for (int t = 0; t < 32; ++t) {
    const int cur = t & 1;
    const u16* kb = &SM[cur * 4096];
    const u16* vb = &SM[8192 + cur * 4096];
    const unsigned mx = mpk[t * 2], my = mpk[t * 2 + 1];
    if (t + 1 < 32) {
      stageK(t + 1, &SM[(cur ^ 1) * 4096]);
      stageV(t + 1, &SM[8192 + (cur ^ 1) * 4096]);
    }
    // shared-K dual QK^T
    f32x4 sa[4], sb[4];
    __builtin_amdgcn_s_setprio(1);
#pragma unroll
    for (int n = 0; n < 4; ++n) {
      const int tr = n * 16 + lr;
      const bf16x8 k0 = *(const bf16x8*)&kb[tr * 64 + ((lg ^ (tr & 7)) << 3)];
      const bf16x8 k1 = *(const bf16x8*)&kb[tr * 64 + (((lg + 4) ^ (tr & 7)) << 3)];
      f32x4 s = z4;
      s = __builtin_amdgcn_mfma_f32_16x16x32_bf16(k0, qfa0, s, 0, 0, 0);
      s = __builtin_amdgcn_mfma_f32_16x16x32_bf16(k1, qfa1, s, 0, 0, 0);
      sa[n] = s;
      f32x4 s2 = z4;
      s2 = __builtin_amdgcn_mfma_f32_16x16x32_bf16(k0, qfb0, s2, 0, 0, 0);
      s2 = __builtin_amdgcn_mfma_f32_16x16x32_bf16(k1, qfb1, s2, 0, 0, 0);
      sb[n] = s2;
    }
    __builtin_amdgcn_s_setprio(0);
    f32x4 wv[4], pb[4];
#pragma unroll
    for (int n = 0; n < 4; ++n)
#pragma unroll
      for (int rr = 0; rr < 4; ++rr) {
        wv[n][rr] = fexp2(fmaf(sa[n][rr], C2, -M2)) * rl_a;
        pb[n][rr] = fexp2(fmaf(sb[n][rr], C2, -M2));
      }
    if ((mx & my) != 0xFFFFFFFFu) {
      maskp(mx, my, wv);
      maskp(mx, my, pb);
    }
#pragma unroll
    for (int n = 0; n < 4; ++n) lsb += (pb[n][0] + pb[n][1]) + (pb[n][2] + pb[n][3]);
    p2tail(t, vb, wv, Wba, oacc);
    if (t + 1 < 32) {
      WAITV(4);  // stage(t+1) done; this round's 4 NT stores stay in flight
      sbar();
    }
  }
  lsb += __shfl_xor(lsb, 16);
  lsb += __shfl_xor(lsb, 32);
  const float rl_b = 1.0f / lsb;
  // O write for qa
#pragma unroll
  for (int n = 0; n < 4; ++n)
#pragma unroll
    for (int r = 0; r < 4; ++r) {
      const int s = sr_a + lg * 4 + r;
      Og[((size_t)(b * 2048 + s)) * 1024 + h * 64 + n * 16 + lr] = f2bf(oacc[n][r]);
    }
  sbar();  // all waves done with loop-B buffer reads

  // ---- loop C: pass2(qb); K+V dbuf, 32 rounds ----
#pragma unroll
  for (int n = 0; n < 4; ++n) oacc[n] = z4;
  stageK(0, &SM[0]);
  stageV(0, &SM[8192]);
  WAITV(0);
  sbar();
  for (int t = 0; t < 32; ++t) {
    const int cur = t & 1;
    const u16* kb = &SM[cur * 4096];
    const u16* vb = &SM[8192 + cur * 4096];
    const unsigned mx = mpk[t * 2], my = mpk[t * 2 + 1];
    if (t + 1 < 32) {
      stageK(t + 1, &SM[(cur ^ 1) * 4096]);
      stageV(t + 1, &SM[8192 + (cur ^ 1) * 4096]);
    }
    f32x4 sc[4];
    qk1(kb, qfb0, qfb1, sc);
    f32x4 wv[4];
#pragma unroll
    for (int n = 0; n < 4; ++n)
#pragma unroll
      for (int rr = 0; rr < 4; ++rr) wv[n][rr] = fexp2(fmaf(sc[n][rr], C2, -M2)) * rl_b;
    maskp(mx, my, wv);
    p2tail(t, vb, wv, Wbb, oacc);
    if (t + 1 < 32) {
      WAITV(4);
      sbar();
    }
  }
  // O write for qb
#pragma unroll
  for (int n = 0; n < 4; ++n)
#pragma unroll
    for (int r = 0; r < 4; ++r) {
      const int s = sr_b + lg * 4 + r;
      Og[((size_t)(b * 2048 + s)) * 1024 + h * 64 + n * 16 + lr] = f2bf(oacc[n][r]);
    }
}

// ---------------- launch ----------------
extern "C" void kernel_launch(void* const* d_in, const int* in_sizes, int n_in,
                              void* d_out, int out_size, void* d_ws, size_t ws_size,
                              hipStream_t stream) {
  const float* x     = (const float*)d_in[0];
  const int*   mask  = (const int*)d_in[1];
  const float* qkv_w = (const float*)d_in[2];
  const float* qkv_b = (const float*)d_in[3];
  const float* wo_w  = (const float*)d_in[4];
  const float* wo_b  = (const float*)d_in[5];
  float* out = (float*)d_out;

  char* ws = (char*)d_ws;
  u16* xb   = (u16*)(ws);                          // 4096x1024
  u16* qwb  = (u16*)(ws + (8u << 20));             // 3072x1024
  u16* wob  = (u16*)(ws + (14u << 20));            // 1024x1024
  u16* qkvb = (u16*)(ws + (16u << 20));            // Q,K: [bh][s][64] bf16
  unsigned* mpack = (unsigned*)(ws + (16u << 20) + 16777216);  // 512B in unused V slot
  u16* vt   = (u16*)(ws + (40u << 20));            // [bh][64][2048] bf16 (QKV epi writes)
  u16* ob   = (u16*)(ws + (48u << 20));            // attn out [4096][1024] bf16

  cvt3<<<8193, 256, 0, stream>>>(x, xb, qkv_w, qwb, wo_w, wob, mask, mpack);
  gemm_bt<1, 128, 128><<<768, 256, 0, stream>>>(xb, qwb, qkv_b, qkvb, vt, 4096, 3072, 1024);
  attn<<<512, 256, 0, stream>>>(qkvb, qkvb + 4194304, vt, mpack, out + 4194304, ob);
  gemm_bt<0, 128, 64><<<512, 256, 0, stream>>>(ob, wob, wo_b, out, nullptr, 4096, 1024, 1024);
}